// Round 17
// baseline (378.227 us; speedup 1.0000x reference)
//
#include <hip/hip_runtime.h>
#include <hip/hip_bf16.h>

using short8 = __attribute__((ext_vector_type(8))) short;
using f32x4  = __attribute__((ext_vector_type(4))) float;

#define S_LEN 4096
#define DM 512

__device__ __forceinline__ unsigned short f2b(float f) {
    unsigned int u = __float_as_uint(f);
    u += 0x7fffu + ((u >> 16) & 1u);
    return (unsigned short)(u >> 16);
}

__device__ __forceinline__ short8 pack8(float4 a, float4 b) {
    short8 r;
    r[0] = (short)f2b(a.x); r[1] = (short)f2b(a.y); r[2] = (short)f2b(a.z); r[3] = (short)f2b(a.w);
    r[4] = (short)f2b(b.x); r[5] = (short)f2b(b.y); r[6] = (short)f2b(b.z); r[7] = (short)f2b(b.w);
    return r;
}

// ---------------- weight transpose+convert: wT[n][k] = bf16(w[k][n]) ----------------
__global__ __launch_bounds__(256) void convert_w(
    const float* __restrict__ w0, const float* __restrict__ w1,
    const float* __restrict__ w2, const float* __restrict__ w3,
    unsigned short* __restrict__ t0, unsigned short* __restrict__ t1,
    unsigned short* __restrict__ t2, unsigned short* __restrict__ t3)
{
    __shared__ float sh[64][65];
    const float* src; unsigned short* dst;
    switch (blockIdx.z) {
        case 0: src = w0; dst = t0; break;
        case 1: src = w1; dst = t1; break;
        case 2: src = w2; dst = t2; break;
        default: src = w3; dst = t3; break;
    }
    int k0 = blockIdx.x * 64, n0 = blockIdx.y * 64;
    int tid = threadIdx.x;
    for (int i = tid; i < 4096; i += 256) {
        int k = i >> 6, n = i & 63;
        sh[k][n] = src[(size_t)(k0 + k) * DM + n0 + n];
    }
    __syncthreads();
    for (int i = tid; i < 4096; i += 256) {
        int n = i >> 6, k = i & 63;
        dst[(size_t)(n0 + n) * DM + k0 + k] = f2b(sh[k][n]);
    }
}

// ---------------- x f32 -> bf16 ----------------
__global__ __launch_bounds__(256) void convert_x(
    const float* __restrict__ x, unsigned short* __restrict__ xb)
{
    size_t i = ((size_t)blockIdx.x * 256 + threadIdx.x) * 8;
    float4 a = *reinterpret_cast<const float4*>(x + i);
    float4 b = *reinterpret_cast<const float4*>(x + i + 4);
    *reinterpret_cast<short8*>(xb + i) = pack8(a, b);
}

// ---------------- gates ----------------
__global__ __launch_bounds__(64) void gates_kernel(
    const float* __restrict__ cs, const float* __restrict__ wg, const float* __restrict__ bg,
    const float* __restrict__ wi, const float* __restrict__ bi,
    float* __restrict__ cwout, float* __restrict__ iwout)
{
    int o = blockIdx.x, b = blockIdx.y, lane = threadIdx.x;
    const float* c = cs + (size_t)b * DM;
    float acc = 0.f;
    if (o < 8) {
        #pragma unroll
        for (int j = 0; j < 8; ++j) { int k = j * 64 + lane; acc += c[k] * wg[(size_t)k * 8 + o]; }
    } else {
        int n = o - 8;
        #pragma unroll
        for (int j = 0; j < 8; ++j) { int k = j * 64 + lane; acc += c[k] * wi[(size_t)k * DM + n]; }
    }
    #pragma unroll
    for (int d = 32; d; d >>= 1) acc += __shfl_xor(acc, d);
    if (lane == 0) {
        if (o < 8) cwout[b * 8 + o] = 1.f / (1.f + __expf(-(acc + bg[o])));
        else       iwout[b * DM + (o - 8)] = 1.f / (1.f + __expf(-(acc + bi[o - 8])));
    }
}

// ---------------- fused QKV GEMM: WT is [1536][512] (wtq|wtk|wtv contiguous) ----------------
__global__ __launch_bounds__(256) void gemm_qkv(
    const unsigned short* __restrict__ A, const unsigned short* __restrict__ WT,
    const float* __restrict__ cw,
    unsigned short* __restrict__ Qb, unsigned short* __restrict__ Kb,
    unsigned short* __restrict__ Vt)
{
    __shared__ unsigned short a_sh[64][72];
    __shared__ unsigned short b_sh[64][72];
    const int m0 = blockIdx.x * 64;
    const int n0g = blockIdx.y * 64;
    const int which = blockIdx.y >> 3;
    const int tid = threadIdx.x;
    const int wave = tid >> 6, lane = tid & 63;
    const int g = lane >> 4, lr = lane & 15;
    const int srow = tid >> 3, skc = (tid & 7) * 8;

    float sq = 1.f;
    if (which == 0) {
        int b = blockIdx.x >> 6;
        int h = blockIdx.y & 7;
        sq = cw[b * 8 + h] * 0.125f * 1.44269504f;
    }

    f32x4 acc[4];
    #pragma unroll
    for (int i = 0; i < 4; ++i) acc[i] = (f32x4){0.f, 0.f, 0.f, 0.f};

    short8 ar[2], br[2];
    #pragma unroll
    for (int cc = 0; cc < 2; ++cc) {
        int row = srow + cc * 32;
        ar[cc] = *reinterpret_cast<const short8*>(A  + (size_t)(m0  + row) * DM + skc);
        br[cc] = *reinterpret_cast<const short8*>(WT + (size_t)(n0g + row) * DM + skc);
    }

    for (int k0 = 0; k0 < 512; k0 += 64) {
        #pragma unroll
        for (int cc = 0; cc < 2; ++cc) {
            int row = srow + cc * 32;
            *reinterpret_cast<short8*>(&a_sh[row][skc]) = ar[cc];
            *reinterpret_cast<short8*>(&b_sh[row][skc]) = br[cc];
        }
        __syncthreads();
        if (k0 + 64 < 512) {
            #pragma unroll
            for (int cc = 0; cc < 2; ++cc) {
                int row = srow + cc * 32;
                ar[cc] = *reinterpret_cast<const short8*>(A  + (size_t)(m0  + row) * DM + k0 + 64 + skc);
                br[cc] = *reinterpret_cast<const short8*>(WT + (size_t)(n0g + row) * DM + k0 + 64 + skc);
            }
        }
        __builtin_amdgcn_s_setprio(1);
        #pragma unroll
        for (int ks = 0; ks < 2; ++ks) {
            short8 af = *reinterpret_cast<const short8*>(&a_sh[wave * 16 + lr][ks * 32 + g * 8]);
            #pragma unroll
            for (int nf = 0; nf < 4; ++nf) {
                short8 bf = *reinterpret_cast<const short8*>(&b_sh[nf * 16 + lr][ks * 32 + g * 8]);
                acc[nf] = __builtin_amdgcn_mfma_f32_16x16x32_bf16(af, bf, acc[nf], 0, 0, 0);
            }
        }
        __builtin_amdgcn_s_setprio(0);
        __syncthreads();
    }

    #pragma unroll
    for (int nf = 0; nf < 4; ++nf) {
        #pragma unroll
        for (int r = 0; r < 4; ++r) {
            int m = m0 + wave * 16 + g * 4 + r;
            int nl = (blockIdx.y & 7) * 64 + nf * 16 + lr;
            unsigned short v = f2b(acc[nf][r] * sq);
            if (which == 0) {
                Qb[(size_t)m * DM + nl] = v;
            } else if (which == 1) {
                Kb[(size_t)m * DM + nl] = v;
            } else {
                int b = m >> 12, s = m & 4095;
                int h = nl >> 6, d = nl & 63;
                Vt[((size_t)(b * 8 + h) * 64 + d) * S_LEN + s] = v;
            }
        }
    }
}

// ---------------- proj GEMM: h = (ctx@wo + bias)*iw + x ----------------
__global__ __launch_bounds__(256) void gemm_proj(
    const unsigned short* __restrict__ A, const unsigned short* __restrict__ WT,
    float* __restrict__ outf, const float* __restrict__ bias,
    const float* __restrict__ iw, const float* __restrict__ xres)
{
    __shared__ unsigned short a_sh[64][72];
    __shared__ unsigned short b_sh[64][72];
    const int m0 = blockIdx.x * 64;
    const int n0 = blockIdx.y * 64;
    const int tid = threadIdx.x;
    const int wave = tid >> 6, lane = tid & 63;
    const int g = lane >> 4, lr = lane & 15;
    const int srow = tid >> 3, skc = (tid & 7) * 8;

    f32x4 acc[4];
    #pragma unroll
    for (int i = 0; i < 4; ++i) acc[i] = (f32x4){0.f, 0.f, 0.f, 0.f};

    short8 ar[2], br[2];
    #pragma unroll
    for (int cc = 0; cc < 2; ++cc) {
        int row = srow + cc * 32;
        ar[cc] = *reinterpret_cast<const short8*>(A  + (size_t)(m0 + row) * DM + skc);
        br[cc] = *reinterpret_cast<const short8*>(WT + (size_t)(n0 + row) * DM + skc);
    }

    for (int k0 = 0; k0 < 512; k0 += 64) {
        #pragma unroll
        for (int cc = 0; cc < 2; ++cc) {
            int row = srow + cc * 32;
            *reinterpret_cast<short8*>(&a_sh[row][skc]) = ar[cc];
            *reinterpret_cast<short8*>(&b_sh[row][skc]) = br[cc];
        }
        __syncthreads();
        if (k0 + 64 < 512) {
            #pragma unroll
            for (int cc = 0; cc < 2; ++cc) {
                int row = srow + cc * 32;
                ar[cc] = *reinterpret_cast<const short8*>(A  + (size_t)(m0 + row) * DM + k0 + 64 + skc);
                br[cc] = *reinterpret_cast<const short8*>(WT + (size_t)(n0 + row) * DM + k0 + 64 + skc);
            }
        }
        __builtin_amdgcn_s_setprio(1);
        #pragma unroll
        for (int ks = 0; ks < 2; ++ks) {
            short8 af = *reinterpret_cast<const short8*>(&a_sh[wave * 16 + lr][ks * 32 + g * 8]);
            #pragma unroll
            for (int nf = 0; nf < 4; ++nf) {
                short8 bf = *reinterpret_cast<const short8*>(&b_sh[nf * 16 + lr][ks * 32 + g * 8]);
                acc[nf] = __builtin_amdgcn_mfma_f32_16x16x32_bf16(af, bf, acc[nf], 0, 0, 0);
            }
        }
        __builtin_amdgcn_s_setprio(0);
        __syncthreads();
    }

    #pragma unroll
    for (int nf = 0; nf < 4; ++nf) {
        #pragma unroll
        for (int r = 0; r < 4; ++r) {
            int m = m0 + wave * 16 + g * 4 + r;
            int n = n0 + nf * 16 + lr;
            int b = m >> 12;
            float v = (acc[nf][r] + bias[n]) * iw[b * DM + n] + xres[(size_t)m * DM + n];
            outf[(size_t)m * DM + n] = v;
        }
    }
}

// ---------------- fused attn: q-tile 128/block, NO K/V LDS staging ----------------
// K/V MFMA fragments are 64B-coalesced directly from global (L2-resident panels,
// XCD-chunked). Software-pipelined 1 tile ahead in regs. Zero barriers in main
// loop (p_sh is wave-private; compiler inserts lgkm waits for its RAW).
__global__ __launch_bounds__(256) void attn_ctx(
    const unsigned short* __restrict__ Qb, const unsigned short* __restrict__ Kb,
    const unsigned short* __restrict__ Vt,
    float* __restrict__ lbuf, unsigned short* __restrict__ ctx)
{
    __shared__ unsigned short p_sh[4][32][72];
    const int wg = blockIdx.x;
    const int logical = (wg & 7) * 64 + (wg >> 3);   // XCD-chunked (512 % 8 == 0)
    const int q0 = (logical & 31) * 128;
    const int bh = logical >> 5;
    const int b = bh >> 3, h = bh & 7;
    const int tid = threadIdx.x, wave = tid >> 6, lane = tid & 63;
    const int g = lane >> 4, lr = lane & 15;

    short8 qf[2][2];
    #pragma unroll
    for (int qq = 0; qq < 2; ++qq) {
        const unsigned short* qp = Qb + (size_t)(b * S_LEN + q0 + wave * 32 + qq * 16 + lr) * DM + h * 64;
        qf[qq][0] = *reinterpret_cast<const short8*>(qp + g * 8);
        qf[qq][1] = *reinterpret_cast<const short8*>(qp + 32 + g * 8);
    }
    short8 onesb;
    #pragma unroll
    for (int i = 0; i < 8; ++i) onesb[i] = (short)0x3F80;   // bf16 1.0

    f32x4 lsum[2];
    f32x4 cacc[2][4];
    #pragma unroll
    for (int qq = 0; qq < 2; ++qq) {
        lsum[qq] = (f32x4){0.f, 0.f, 0.f, 0.f};
        #pragma unroll
        for (int i = 0; i < 4; ++i) cacc[qq][i] = (f32x4){0.f, 0.f, 0.f, 0.f};
    }

    // per-lane fragment bases:
    // K frag (f,ks) at tile kv0: Kl + (kv0 + f*16)*DM + ks*32
    // V frag (df,ks) at tile kv0: Vl + (df*16)*S_LEN + kv0 + ks*32
    const unsigned short* Kl = Kb + (size_t)(b * S_LEN + lr) * DM + h * 64 + g * 8;
    const unsigned short* Vl = Vt + ((size_t)bh * 64 + lr) * S_LEN + g * 8;

    short8 krf[8], vrf[8];
    #pragma unroll
    for (int f = 0; f < 4; ++f)
        #pragma unroll
        for (int ks = 0; ks < 2; ++ks)
            krf[f * 2 + ks] = *reinterpret_cast<const short8*>(Kl + (size_t)(f * 16) * DM + ks * 32);
    #pragma unroll
    for (int df = 0; df < 4; ++df)
        #pragma unroll
        for (int ks = 0; ks < 2; ++ks)
            vrf[df * 2 + ks] = *reinterpret_cast<const short8*>(Vl + (size_t)(df * 16) * S_LEN + ks * 32);

    for (int t = 0; t < 64; ++t) {
        const int kv0 = t * 64;
        // QK(t) from krf regs
        f32x4 st[2][4];
        #pragma unroll
        for (int qq = 0; qq < 2; ++qq)
            #pragma unroll
            for (int f = 0; f < 4; ++f) st[qq][f] = (f32x4){0.f, 0.f, 0.f, 0.f};
        __builtin_amdgcn_s_setprio(1);
        #pragma unroll
        for (int ks = 0; ks < 2; ++ks) {
            #pragma unroll
            for (int f = 0; f < 4; ++f) {
                #pragma unroll
                for (int qq = 0; qq < 2; ++qq)
                    st[qq][f] = __builtin_amdgcn_mfma_f32_16x16x32_bf16(krf[f * 2 + ks], qf[qq][ks], st[qq][f], 0, 0, 0);
            }
        }
        __builtin_amdgcn_s_setprio(0);
        // prefetch K fragments for t+1 (L2-hit; consumed next iteration's QK)
        if (t + 1 < 64) {
            #pragma unroll
            for (int f = 0; f < 4; ++f)
                #pragma unroll
                for (int ks = 0; ks < 2; ++ks)
                    krf[f * 2 + ks] = *reinterpret_cast<const short8*>(Kl + (size_t)(kv0 + 64 + f * 16) * DM + ks * 32);
        }
        // P = exp2(st); pack quads -> b64 into p_sh[wave][qq*16+lr][...]
        #pragma unroll
        for (int qq = 0; qq < 2; ++qq) {
            #pragma unroll
            for (int f = 0; f < 4; ++f) {
                float p0 = __builtin_amdgcn_exp2f(st[qq][f][0]);
                float p1 = __builtin_amdgcn_exp2f(st[qq][f][1]);
                float p2 = __builtin_amdgcn_exp2f(st[qq][f][2]);
                float p3 = __builtin_amdgcn_exp2f(st[qq][f][3]);
                unsigned u0, u1;
                asm("v_cvt_pk_bf16_f32 %0, %1, %2" : "=v"(u0) : "v"(p0), "v"(p1));
                asm("v_cvt_pk_bf16_f32 %0, %1, %2" : "=v"(u1) : "v"(p2), "v"(p3));
                uint2 pv; pv.x = u0; pv.y = u1;
                *reinterpret_cast<uint2*>(&p_sh[wave][qq * 16 + lr][f * 16 + g * 4]) = pv;
            }
        }
        // PV(t) + lsum from p_sh + vrf regs
        __builtin_amdgcn_s_setprio(1);
        #pragma unroll
        for (int ks = 0; ks < 2; ++ks) {
            short8 pf[2];
            #pragma unroll
            for (int qq = 0; qq < 2; ++qq)
                pf[qq] = *reinterpret_cast<const short8*>(&p_sh[wave][qq * 16 + lr][ks * 32 + g * 8]);
            #pragma unroll
            for (int qq = 0; qq < 2; ++qq)
                lsum[qq] = __builtin_amdgcn_mfma_f32_16x16x32_bf16(pf[qq], onesb, lsum[qq], 0, 0, 0);
            #pragma unroll
            for (int df = 0; df < 4; ++df) {
                #pragma unroll
                for (int qq = 0; qq < 2; ++qq)
                    cacc[qq][df] = __builtin_amdgcn_mfma_f32_16x16x32_bf16(pf[qq], vrf[df * 2 + ks], cacc[qq][df], 0, 0, 0);
            }
        }
        __builtin_amdgcn_s_setprio(0);
        // prefetch V fragments for t+1
        if (t + 1 < 64) {
            #pragma unroll
            for (int df = 0; df < 4; ++df)
                #pragma unroll
                for (int ks = 0; ks < 2; ++ks)
                    vrf[df * 2 + ks] = *reinterpret_cast<const short8*>(Vl + (size_t)(df * 16) * S_LEN + kv0 + 64 + ks * 32);
        }
    }
    #pragma unroll
    for (int qq = 0; qq < 2; ++qq) {
        float rl[4];
        #pragma unroll
        for (int r = 0; r < 4; ++r) rl[r] = 1.f / lsum[qq][r];
        if (lr == 0) {
            #pragma unroll
            for (int r = 0; r < 4; ++r)
                lbuf[bh * S_LEN + q0 + wave * 32 + qq * 16 + g * 4 + r] = lsum[qq][r];
        }
        #pragma unroll
        for (int df = 0; df < 4; ++df) {
            #pragma unroll
            for (int r = 0; r < 4; ++r) {
                int q = q0 + wave * 32 + qq * 16 + g * 4 + r;
                ctx[(size_t)(b * S_LEN + q) * DM + h * 64 + df * 16 + lr] = f2b(cacc[qq][df][r] * rl[r]);
            }
        }
    }
}

// ---------------- attn mean over heads (swapped QK^T -> float4 stores, scalar la2) ----------------
__global__ __launch_bounds__(256) void attn_mean(
    const unsigned short* __restrict__ Qb, const unsigned short* __restrict__ Kb,
    const float* __restrict__ lbuf, float* __restrict__ outmean)
{
    __shared__ unsigned short k_sh[32][520];
    const int wg = blockIdx.x;
    const int logical = (wg & 7) * 128 + (wg >> 3);   // XCD-chunked
    const int q0 = (logical & 63) * 64;
    const int kcb = logical >> 6;                      // 0..15
    const int kc0 = (kcb & 7) * 512;
    const int b = kcb >> 3;
    const int tid = threadIdx.x, wave = tid >> 6, lane = tid & 63;
    const int g = lane >> 4, lr = lane & 15;
    const int srow = tid >> 6, scol = (tid & 63) * 8;

    const int qrow = q0 + wave * 16 + lr;              // this lane's q row
    float la2[8];
    #pragma unroll
    for (int h = 0; h < 8; ++h)
        la2[h] = -log2f(lbuf[(b * 8 + h) * S_LEN + qrow]) - 3.0f;

    const unsigned short* qbase = Qb + (size_t)(b * S_LEN + qrow) * DM;
    const unsigned short* Kbase = Kb + (size_t)(b * S_LEN) * DM;
    float* obase = outmean + (size_t)(b * S_LEN + qrow) * S_LEN;

    short8 stg[8];
    #pragma unroll
    for (int i = 0; i < 8; ++i) {
        int row = srow + i * 4;
        stg[i] = *reinterpret_cast<const short8*>(Kbase + (size_t)(kc0 + row) * DM + scol);
    }

    for (int t = 0; t < 16; ++t) {
        int kv0 = kc0 + t * 32;
        #pragma unroll
        for (int i = 0; i < 8; ++i) {
            int row = srow + i * 4;
            *reinterpret_cast<short8*>(&k_sh[row][scol]) = stg[i];
        }
        __syncthreads();
        if (t + 1 < 16) {
            #pragma unroll
            for (int i = 0; i < 8; ++i) {
                int row = srow + i * 4;
                stg[i] = *reinterpret_cast<const short8*>(Kbase + (size_t)(kv0 + 32 + row) * DM + scol);
            }
        }
        float macc[2][4];
        #pragma unroll
        for (int f = 0; f < 2; ++f)
            #pragma unroll
            for (int r = 0; r < 4; ++r) macc[f][r] = 0.f;
        #pragma unroll
        for (int h = 0; h < 8; ++h) {
            const unsigned short* qp = qbase + h * 64;
            short8 qf0 = *reinterpret_cast<const short8*>(qp + g * 8);
            short8 qf1 = *reinterpret_cast<const short8*>(qp + 32 + g * 8);
            f32x4 s[2];
            s[0] = (f32x4){0.f, 0.f, 0.f, 0.f};
            s[1] = (f32x4){0.f, 0.f, 0.f, 0.f};
            __builtin_amdgcn_s_setprio(1);
            #pragma unroll
            for (int f = 0; f < 2; ++f) {
                short8 kf0 = *reinterpret_cast<const short8*>(&k_sh[f * 16 + lr][h * 64 + g * 8]);
                s[f] = __builtin_amdgcn_mfma_f32_16x16x32_bf16(kf0, qf0, s[f], 0, 0, 0);
                short8 kf1 = *reinterpret_cast<const short8*>(&k_sh[f * 16 + lr][h * 64 + 32 + g * 8]);
                s[f] = __builtin_amdgcn_mfma_f32_16x16x32_bf16(kf1, qf1, s[f], 0, 0, 0);
            }
            __builtin_amdgcn_s_setprio(0);
            #pragma unroll
            for (int f = 0; f < 2; ++f)
                #pragma unroll
                for (int r = 0; r < 4; ++r)
                    macc[f][r] += __builtin_amdgcn_exp2f(s[f][r] + la2[h]);
        }
        #pragma unroll
        for (int f = 0; f < 2; ++f) {
            float4 ov;
            ov.x = macc[f][0]; ov.y = macc[f][1]; ov.z = macc[f][2]; ov.w = macc[f][3];
            *reinterpret_cast<float4*>(obase + kv0 + f * 16 + g * 4) = ov;
        }
        __syncthreads();
    }
}

// ---------------- LayerNorm (one wave per row of 512) ----------------
__global__ __launch_bounds__(64) void ln_kernel(
    const float* __restrict__ hbuf, const float* __restrict__ gamma,
    const float* __restrict__ beta, float* __restrict__ dout)
{
    int row = blockIdx.x, lane = threadIdx.x;
    const float* hp = hbuf + (size_t)row * DM + lane * 8;
    float4 v0 = *reinterpret_cast<const float4*>(hp);
    float4 v1 = *reinterpret_cast<const float4*>(hp + 4);
    float s = v0.x + v0.y + v0.z + v0.w + v1.x + v1.y + v1.z + v1.w;
    float ss = v0.x * v0.x + v0.y * v0.y + v0.z * v0.z + v0.w * v0.w
             + v1.x * v1.x + v1.y * v1.y + v1.z * v1.z + v1.w * v1.w;
    #pragma unroll
    for (int d = 32; d; d >>= 1) { s += __shfl_xor(s, d); ss += __shfl_xor(ss, d); }
    float mu = s * (1.f / 512.f);
    float var = ss * (1.f / 512.f) - mu * mu;
    float rstd = rsqrtf(var + 1e-5f);
    float4 g0 = *reinterpret_cast<const float4*>(gamma + lane * 8);
    float4 g1 = *reinterpret_cast<const float4*>(gamma + lane * 8 + 4);
    float4 b0 = *reinterpret_cast<const float4*>(beta + lane * 8);
    float4 b1 = *reinterpret_cast<const float4*>(beta + lane * 8 + 4);
    float4 o0, o1;
    o0.x = (v0.x - mu) * rstd * g0.x + b0.x;
    o0.y = (v0.y - mu) * rstd * g0.y + b0.y;
    o0.z = (v0.z - mu) * rstd * g0.z + b0.z;
    o0.w = (v0.w - mu) * rstd * g0.w + b0.w;
    o1.x = (v1.x - mu) * rstd * g1.x + b1.x;
    o1.y = (v1.y - mu) * rstd * g1.y + b1.y;
    o1.z = (v1.z - mu) * rstd * g1.z + b1.z;
    o1.w = (v1.w - mu) * rstd * g1.w + b1.w;
    float* op = dout + (size_t)row * DM + lane * 8;
    *reinterpret_cast<float4*>(op) = o0;
    *reinterpret_cast<float4*>(op + 4) = o1;
}

extern "C" void kernel_launch(void* const* d_in, const int* in_sizes, int n_in,
                              void* d_out, int out_size, void* d_ws, size_t ws_size,
                              hipStream_t stream)
{
    const float* x   = (const float*)d_in[0];
    const float* cs  = (const float*)d_in[1];
    const float* wq  = (const float*)d_in[2];
    const float* wk  = (const float*)d_in[3];
    const float* wv  = (const float*)d_in[4];
    const float* wo  = (const float*)d_in[5];
    const float* bo  = (const float*)d_in[6];
    const float* wg  = (const float*)d_in[7];
    const float* bg  = (const float*)d_in[8];
    const float* wi  = (const float*)d_in[9];
    const float* bi  = (const float*)d_in[10];
    const float* gam = (const float*)d_in[11];
    const float* bet = (const float*)d_in[12];

    float* out = (float*)d_out;
    float* outmean = out + (size_t)2 * S_LEN * DM;

    char* ws = (char*)d_ws;
    size_t off = 0;
    auto alloc = [&](size_t bytes) { void* p = ws + off; off += (bytes + 255) & ~(size_t)255; return p; };

    unsigned short* wtq = (unsigned short*)alloc((size_t)DM * DM * 2);   // contiguous:
    unsigned short* wtk = (unsigned short*)alloc((size_t)DM * DM * 2);   // wtq|wtk|wtv form
    unsigned short* wtv = (unsigned short*)alloc((size_t)DM * DM * 2);   // a [1536][512] block
    unsigned short* wto = (unsigned short*)alloc((size_t)DM * DM * 2);
    unsigned short* xb  = (unsigned short*)alloc((size_t)2 * S_LEN * DM * 2);
    unsigned short* Qb  = (unsigned short*)alloc((size_t)2 * S_LEN * DM * 2);
    unsigned short* Kb  = (unsigned short*)alloc((size_t)2 * S_LEN * DM * 2);
    unsigned short* Vt  = (unsigned short*)alloc((size_t)2 * S_LEN * DM * 2);
    unsigned short* ctx = (unsigned short*)alloc((size_t)2 * S_LEN * DM * 2);
    float* lbuf = (float*)alloc((size_t)16 * S_LEN * 4);
    float* cwb  = (float*)alloc(64);
    float* iwb  = (float*)alloc((size_t)2 * DM * 4);
    // hbuf aliases Qb+Kb (16 MB f32; both dead after attn_mean; stream-ordered)
    float* hbuf = (float*)Qb;

    convert_w<<<dim3(8, 8, 4), 256, 0, stream>>>(wq, wk, wv, wo, wtq, wtk, wtv, wto);
    convert_x<<<dim3(2048), 256, 0, stream>>>(x, xb);
    gates_kernel<<<dim3(520, 2), 64, 0, stream>>>(cs, wg, bg, wi, bi, cwb, iwb);

    gemm_qkv<<<dim3(128, 24), 256, 0, stream>>>(xb, wtq, cwb, Qb, Kb, Vt);

    attn_ctx<<<dim3(512), 256, 0, stream>>>(Qb, Kb, Vt, lbuf, ctx);
    attn_mean<<<dim3(1024), 256, 0, stream>>>(Qb, Kb, lbuf, outmean);

    gemm_proj<<<dim3(128, 8), 256, 0, stream>>>(ctx, wto, hbuf, bo, iwb, x);
    ln_kernel<<<dim3(2 * S_LEN), 64, 0, stream>>>(hbuf, gam, bet, out);
}

// Round 18
// 235.894 us; speedup vs baseline: 1.6034x; 1.6034x over previous
//
#include <hip/hip_runtime.h>
#include <hip/hip_bf16.h>

using short8 = __attribute__((ext_vector_type(8))) short;
using f32x4  = __attribute__((ext_vector_type(4))) float;

#define S_LEN 4096
#define DM 512

__device__ __forceinline__ unsigned short f2b(float f) {
    unsigned int u = __float_as_uint(f);
    u += 0x7fffu + ((u >> 16) & 1u);
    return (unsigned short)(u >> 16);
}

__device__ __forceinline__ short8 pack8(float4 a, float4 b) {
    short8 r;
    r[0] = (short)f2b(a.x); r[1] = (short)f2b(a.y); r[2] = (short)f2b(a.z); r[3] = (short)f2b(a.w);
    r[4] = (short)f2b(b.x); r[5] = (short)f2b(b.y); r[6] = (short)f2b(b.z); r[7] = (short)f2b(b.w);
    return r;
}

// ---------------- weight transpose+convert: wT[n][k] = bf16(w[k][n]) ----------------
__global__ __launch_bounds__(256) void convert_w(
    const float* __restrict__ w0, const float* __restrict__ w1,
    const float* __restrict__ w2, const float* __restrict__ w3,
    unsigned short* __restrict__ t0, unsigned short* __restrict__ t1,
    unsigned short* __restrict__ t2, unsigned short* __restrict__ t3)
{
    __shared__ float sh[64][65];
    const float* src; unsigned short* dst;
    switch (blockIdx.z) {
        case 0: src = w0; dst = t0; break;
        case 1: src = w1; dst = t1; break;
        case 2: src = w2; dst = t2; break;
        default: src = w3; dst = t3; break;
    }
    int k0 = blockIdx.x * 64, n0 = blockIdx.y * 64;
    int tid = threadIdx.x;
    for (int i = tid; i < 4096; i += 256) {
        int k = i >> 6, n = i & 63;
        sh[k][n] = src[(size_t)(k0 + k) * DM + n0 + n];
    }
    __syncthreads();
    for (int i = tid; i < 4096; i += 256) {
        int n = i >> 6, k = i & 63;
        dst[(size_t)(n0 + n) * DM + k0 + k] = f2b(sh[k][n]);
    }
}

// ---------------- x f32 -> bf16 ----------------
__global__ __launch_bounds__(256) void convert_x(
    const float* __restrict__ x, unsigned short* __restrict__ xb)
{
    size_t i = ((size_t)blockIdx.x * 256 + threadIdx.x) * 8;
    float4 a = *reinterpret_cast<const float4*>(x + i);
    float4 b = *reinterpret_cast<const float4*>(x + i + 4);
    *reinterpret_cast<short8*>(xb + i) = pack8(a, b);
}

// ---------------- gates ----------------
__global__ __launch_bounds__(64) void gates_kernel(
    const float* __restrict__ cs, const float* __restrict__ wg, const float* __restrict__ bg,
    const float* __restrict__ wi, const float* __restrict__ bi,
    float* __restrict__ cwout, float* __restrict__ iwout)
{
    int o = blockIdx.x, b = blockIdx.y, lane = threadIdx.x;
    const float* c = cs + (size_t)b * DM;
    float acc = 0.f;
    if (o < 8) {
        #pragma unroll
        for (int j = 0; j < 8; ++j) { int k = j * 64 + lane; acc += c[k] * wg[(size_t)k * 8 + o]; }
    } else {
        int n = o - 8;
        #pragma unroll
        for (int j = 0; j < 8; ++j) { int k = j * 64 + lane; acc += c[k] * wi[(size_t)k * DM + n]; }
    }
    #pragma unroll
    for (int d = 32; d; d >>= 1) acc += __shfl_xor(acc, d);
    if (lane == 0) {
        if (o < 8) cwout[b * 8 + o] = 1.f / (1.f + __expf(-(acc + bg[o])));
        else       iwout[b * DM + (o - 8)] = 1.f / (1.f + __expf(-(acc + bi[o - 8])));
    }
}

// ---------------- fused QKV GEMM, 128-row M-tile: WT is [1536][512] ----------------
// blockIdx.y 0-7 -> Q (prescaled); 8-15 -> K; 16-23 -> V transposed.
__global__ __launch_bounds__(256) void gemm_qkv(
    const unsigned short* __restrict__ A, const unsigned short* __restrict__ WT,
    const float* __restrict__ cw,
    unsigned short* __restrict__ Qb, unsigned short* __restrict__ Kb,
    unsigned short* __restrict__ Vt)
{
    __shared__ unsigned short a_sh[128][72];
    __shared__ unsigned short b_sh[64][72];
    const int m0 = blockIdx.x * 128;
    const int n0g = blockIdx.y * 64;
    const int which = blockIdx.y >> 3;
    const int tid = threadIdx.x;
    const int wave = tid >> 6, lane = tid & 63;
    const int g = lane >> 4, lr = lane & 15;
    const int srow = tid >> 3, skc = (tid & 7) * 8;

    float sq = 1.f;
    if (which == 0) {
        int b = blockIdx.x >> 5;               // m0 >> 12
        int h = blockIdx.y & 7;
        sq = cw[b * 8 + h] * 0.125f * 1.44269504f;
    }

    f32x4 acc[2][4];
    #pragma unroll
    for (int qq = 0; qq < 2; ++qq)
        #pragma unroll
        for (int i = 0; i < 4; ++i) acc[qq][i] = (f32x4){0.f, 0.f, 0.f, 0.f};

    short8 ar[4], br[2];
    #pragma unroll
    for (int cc = 0; cc < 4; ++cc)
        ar[cc] = *reinterpret_cast<const short8*>(A  + (size_t)(m0  + srow + cc * 32) * DM + skc);
    #pragma unroll
    for (int cc = 0; cc < 2; ++cc)
        br[cc] = *reinterpret_cast<const short8*>(WT + (size_t)(n0g + srow + cc * 32) * DM + skc);

    for (int k0 = 0; k0 < 512; k0 += 64) {
        #pragma unroll
        for (int cc = 0; cc < 4; ++cc)
            *reinterpret_cast<short8*>(&a_sh[srow + cc * 32][skc]) = ar[cc];
        #pragma unroll
        for (int cc = 0; cc < 2; ++cc)
            *reinterpret_cast<short8*>(&b_sh[srow + cc * 32][skc]) = br[cc];
        __syncthreads();
        if (k0 + 64 < 512) {
            #pragma unroll
            for (int cc = 0; cc < 4; ++cc)
                ar[cc] = *reinterpret_cast<const short8*>(A  + (size_t)(m0  + srow + cc * 32) * DM + k0 + 64 + skc);
            #pragma unroll
            for (int cc = 0; cc < 2; ++cc)
                br[cc] = *reinterpret_cast<const short8*>(WT + (size_t)(n0g + srow + cc * 32) * DM + k0 + 64 + skc);
        }
        __builtin_amdgcn_s_setprio(1);
        #pragma unroll
        for (int ks = 0; ks < 2; ++ks) {
            short8 af[2];
            #pragma unroll
            for (int qq = 0; qq < 2; ++qq)
                af[qq] = *reinterpret_cast<const short8*>(&a_sh[wave * 32 + qq * 16 + lr][ks * 32 + g * 8]);
            #pragma unroll
            for (int nf = 0; nf < 4; ++nf) {
                short8 bf = *reinterpret_cast<const short8*>(&b_sh[nf * 16 + lr][ks * 32 + g * 8]);
                #pragma unroll
                for (int qq = 0; qq < 2; ++qq)
                    acc[qq][nf] = __builtin_amdgcn_mfma_f32_16x16x32_bf16(af[qq], bf, acc[qq][nf], 0, 0, 0);
            }
        }
        __builtin_amdgcn_s_setprio(0);
        __syncthreads();
    }

    #pragma unroll
    for (int qq = 0; qq < 2; ++qq) {
        #pragma unroll
        for (int nf = 0; nf < 4; ++nf) {
            #pragma unroll
            for (int r = 0; r < 4; ++r) {
                int m = m0 + wave * 32 + qq * 16 + g * 4 + r;
                int nl = (blockIdx.y & 7) * 64 + nf * 16 + lr;
                unsigned short v = f2b(acc[qq][nf][r] * sq);
                if (which == 0) {
                    Qb[(size_t)m * DM + nl] = v;
                } else if (which == 1) {
                    Kb[(size_t)m * DM + nl] = v;
                } else {
                    int b = m >> 12, s = m & 4095;
                    int h = nl >> 6, d = nl & 63;
                    Vt[((size_t)(b * 8 + h) * 64 + d) * S_LEN + s] = v;
                }
            }
        }
    }
}

// ---------------- proj GEMM, 128-row M-tile: h = (ctx@wo + bias)*iw + x ----------------
__global__ __launch_bounds__(256) void gemm_proj(
    const unsigned short* __restrict__ A, const unsigned short* __restrict__ WT,
    float* __restrict__ outf, const float* __restrict__ bias,
    const float* __restrict__ iw, const float* __restrict__ xres)
{
    __shared__ unsigned short a_sh[128][72];
    __shared__ unsigned short b_sh[64][72];
    const int m0 = blockIdx.x * 128;
    const int n0 = blockIdx.y * 64;
    const int tid = threadIdx.x;
    const int wave = tid >> 6, lane = tid & 63;
    const int g = lane >> 4, lr = lane & 15;
    const int srow = tid >> 3, skc = (tid & 7) * 8;

    f32x4 acc[2][4];
    #pragma unroll
    for (int qq = 0; qq < 2; ++qq)
        #pragma unroll
        for (int i = 0; i < 4; ++i) acc[qq][i] = (f32x4){0.f, 0.f, 0.f, 0.f};

    short8 ar[4], br[2];
    #pragma unroll
    for (int cc = 0; cc < 4; ++cc)
        ar[cc] = *reinterpret_cast<const short8*>(A  + (size_t)(m0 + srow + cc * 32) * DM + skc);
    #pragma unroll
    for (int cc = 0; cc < 2; ++cc)
        br[cc] = *reinterpret_cast<const short8*>(WT + (size_t)(n0 + srow + cc * 32) * DM + skc);

    for (int k0 = 0; k0 < 512; k0 += 64) {
        #pragma unroll
        for (int cc = 0; cc < 4; ++cc)
            *reinterpret_cast<short8*>(&a_sh[srow + cc * 32][skc]) = ar[cc];
        #pragma unroll
        for (int cc = 0; cc < 2; ++cc)
            *reinterpret_cast<short8*>(&b_sh[srow + cc * 32][skc]) = br[cc];
        __syncthreads();
        if (k0 + 64 < 512) {
            #pragma unroll
            for (int cc = 0; cc < 4; ++cc)
                ar[cc] = *reinterpret_cast<const short8*>(A  + (size_t)(m0 + srow + cc * 32) * DM + k0 + 64 + skc);
            #pragma unroll
            for (int cc = 0; cc < 2; ++cc)
                br[cc] = *reinterpret_cast<const short8*>(WT + (size_t)(n0 + srow + cc * 32) * DM + k0 + 64 + skc);
        }
        __builtin_amdgcn_s_setprio(1);
        #pragma unroll
        for (int ks = 0; ks < 2; ++ks) {
            short8 af[2];
            #pragma unroll
            for (int qq = 0; qq < 2; ++qq)
                af[qq] = *reinterpret_cast<const short8*>(&a_sh[wave * 32 + qq * 16 + lr][ks * 32 + g * 8]);
            #pragma unroll
            for (int nf = 0; nf < 4; ++nf) {
                short8 bf = *reinterpret_cast<const short8*>(&b_sh[nf * 16 + lr][ks * 32 + g * 8]);
                #pragma unroll
                for (int qq = 0; qq < 2; ++qq)
                    acc[qq][nf] = __builtin_amdgcn_mfma_f32_16x16x32_bf16(af[qq], bf, acc[qq][nf], 0, 0, 0);
            }
        }
        __builtin_amdgcn_s_setprio(0);
        __syncthreads();
    }

    #pragma unroll
    for (int qq = 0; qq < 2; ++qq) {
        #pragma unroll
        for (int nf = 0; nf < 4; ++nf) {
            #pragma unroll
            for (int r = 0; r < 4; ++r) {
                int m = m0 + wave * 32 + qq * 16 + g * 4 + r;
                int n = n0 + nf * 16 + lr;
                int b = m >> 12;
                float v = (acc[qq][nf][r] + bias[n]) * iw[b * DM + n] + xres[(size_t)m * DM + n];
                outf[(size_t)m * DM + n] = v;
            }
        }
    }
}

// ---------------- fused attn: q-tile 128/block (r15 verified form) ----------------
__global__ __launch_bounds__(256) void attn_ctx(
    const unsigned short* __restrict__ Qb, const unsigned short* __restrict__ Kb,
    const unsigned short* __restrict__ Vt,
    float* __restrict__ lbuf, unsigned short* __restrict__ ctx)
{
    __shared__ unsigned short k_sh[64][72];
    __shared__ unsigned short v_sh[64][72];
    __shared__ unsigned short p_sh[4][32][72];
    const int wg = blockIdx.x;
    const int logical = (wg & 7) * 64 + (wg >> 3);   // XCD-chunked (512 % 8 == 0)
    const int q0 = (logical & 31) * 128;
    const int bh = logical >> 5;
    const int b = bh >> 3, h = bh & 7;
    const int tid = threadIdx.x, wave = tid >> 6, lane = tid & 63;
    const int g = lane >> 4, lr = lane & 15;
    const int srow = tid >> 3, skc = (tid & 7) * 8;

    short8 qf[2][2];
    #pragma unroll
    for (int qq = 0; qq < 2; ++qq) {
        const unsigned short* qp = Qb + (size_t)(b * S_LEN + q0 + wave * 32 + qq * 16 + lr) * DM + h * 64;
        qf[qq][0] = *reinterpret_cast<const short8*>(qp + g * 8);
        qf[qq][1] = *reinterpret_cast<const short8*>(qp + 32 + g * 8);
    }
    short8 onesb;
    #pragma unroll
    for (int i = 0; i < 8; ++i) onesb[i] = (short)0x3F80;   // bf16 1.0

    f32x4 lsum[2];
    f32x4 cacc[2][4];
    #pragma unroll
    for (int qq = 0; qq < 2; ++qq) {
        lsum[qq] = (f32x4){0.f, 0.f, 0.f, 0.f};
        #pragma unroll
        for (int i = 0; i < 4; ++i) cacc[qq][i] = (f32x4){0.f, 0.f, 0.f, 0.f};
    }

    const unsigned short* Kbase = Kb + (size_t)(b * S_LEN) * DM + h * 64;
    const unsigned short* Vbase = Vt + ((size_t)bh * 64) * S_LEN;

    short8 kr[2], vr[2];
    #pragma unroll
    for (int cc = 0; cc < 2; ++cc) {
        int row = srow + cc * 32;
        kr[cc] = *reinterpret_cast<const short8*>(Kbase + (size_t)row * DM + skc);
        vr[cc] = *reinterpret_cast<const short8*>(Vbase + (size_t)row * S_LEN + skc);
    }

    for (int kv0 = 0; kv0 < S_LEN; kv0 += 64) {
        #pragma unroll
        for (int cc = 0; cc < 2; ++cc) {
            int row = srow + cc * 32;
            *reinterpret_cast<short8*>(&k_sh[row][skc]) = kr[cc];
            *reinterpret_cast<short8*>(&v_sh[row][skc]) = vr[cc];
        }
        __syncthreads();
        f32x4 st[2][4];
        #pragma unroll
        for (int qq = 0; qq < 2; ++qq)
            #pragma unroll
            for (int f = 0; f < 4; ++f) st[qq][f] = (f32x4){0.f, 0.f, 0.f, 0.f};
        __builtin_amdgcn_s_setprio(1);
        #pragma unroll
        for (int ks = 0; ks < 2; ++ks) {
            #pragma unroll
            for (int f = 0; f < 4; ++f) {
                short8 kf = *reinterpret_cast<const short8*>(&k_sh[f * 16 + lr][ks * 32 + g * 8]);
                #pragma unroll
                for (int qq = 0; qq < 2; ++qq)
                    st[qq][f] = __builtin_amdgcn_mfma_f32_16x16x32_bf16(kf, qf[qq][ks], st[qq][f], 0, 0, 0);
            }
        }
        __builtin_amdgcn_s_setprio(0);
        // prefetch next K/V tile into regs (latency hides under softmax+PV)
        if (kv0 + 64 < S_LEN) {
            #pragma unroll
            for (int cc = 0; cc < 2; ++cc) {
                int row = srow + cc * 32;
                kr[cc] = *reinterpret_cast<const short8*>(Kbase + (size_t)(kv0 + 64 + row) * DM + skc);
                vr[cc] = *reinterpret_cast<const short8*>(Vbase + (size_t)row * S_LEN + kv0 + 64 + skc);
            }
        }
        // P = exp2(st); pack quads -> b64 into p_sh[wave][qq*16+lr][...]
        #pragma unroll
        for (int qq = 0; qq < 2; ++qq) {
            #pragma unroll
            for (int f = 0; f < 4; ++f) {
                float p0 = __builtin_amdgcn_exp2f(st[qq][f][0]);
                float p1 = __builtin_amdgcn_exp2f(st[qq][f][1]);
                float p2 = __builtin_amdgcn_exp2f(st[qq][f][2]);
                float p3 = __builtin_amdgcn_exp2f(st[qq][f][3]);
                unsigned u0, u1;
                asm("v_cvt_pk_bf16_f32 %0, %1, %2" : "=v"(u0) : "v"(p0), "v"(p1));
                asm("v_cvt_pk_bf16_f32 %0, %1, %2" : "=v"(u1) : "v"(p2), "v"(p3));
                uint2 pv; pv.x = u0; pv.y = u1;
                *reinterpret_cast<uint2*>(&p_sh[wave][qq * 16 + lr][f * 16 + g * 4]) = pv;
            }
        }
        __builtin_amdgcn_s_setprio(1);
        #pragma unroll
        for (int ks = 0; ks < 2; ++ks) {
            short8 pf[2];
            #pragma unroll
            for (int qq = 0; qq < 2; ++qq)
                pf[qq] = *reinterpret_cast<const short8*>(&p_sh[wave][qq * 16 + lr][ks * 32 + g * 8]);
            #pragma unroll
            for (int qq = 0; qq < 2; ++qq)
                lsum[qq] = __builtin_amdgcn_mfma_f32_16x16x32_bf16(pf[qq], onesb, lsum[qq], 0, 0, 0);
            #pragma unroll
            for (int df = 0; df < 4; ++df) {
                short8 vf = *reinterpret_cast<const short8*>(&v_sh[df * 16 + lr][ks * 32 + g * 8]);
                #pragma unroll
                for (int qq = 0; qq < 2; ++qq)
                    cacc[qq][df] = __builtin_amdgcn_mfma_f32_16x16x32_bf16(pf[qq], vf, cacc[qq][df], 0, 0, 0);
            }
        }
        __builtin_amdgcn_s_setprio(0);
        __syncthreads();
    }
    #pragma unroll
    for (int qq = 0; qq < 2; ++qq) {
        float rl[4];
        #pragma unroll
        for (int r = 0; r < 4; ++r) rl[r] = 1.f / lsum[qq][r];
        if (lr == 0) {
            #pragma unroll
            for (int r = 0; r < 4; ++r)
                lbuf[bh * S_LEN + q0 + wave * 32 + qq * 16 + g * 4 + r] = lsum[qq][r];
        }
        #pragma unroll
        for (int df = 0; df < 4; ++df) {
            #pragma unroll
            for (int r = 0; r < 4; ++r) {
                int q = q0 + wave * 32 + qq * 16 + g * 4 + r;
                ctx[(size_t)(b * S_LEN + q) * DM + h * 64 + df * 16 + lr] = f2b(cacc[qq][df][r] * rl[r]);
            }
        }
    }
}

// ---------------- attn mean over heads (swapped QK^T -> float4 stores, scalar la2) ----------------
__global__ __launch_bounds__(256) void attn_mean(
    const unsigned short* __restrict__ Qb, const unsigned short* __restrict__ Kb,
    const float* __restrict__ lbuf, float* __restrict__ outmean)
{
    __shared__ unsigned short k_sh[32][520];
    const int wg = blockIdx.x;
    const int logical = (wg & 7) * 128 + (wg >> 3);   // XCD-chunked
    const int q0 = (logical & 63) * 64;
    const int kcb = logical >> 6;                      // 0..15
    const int kc0 = (kcb & 7) * 512;
    const int b = kcb >> 3;
    const int tid = threadIdx.x, wave = tid >> 6, lane = tid & 63;
    const int g = lane >> 4, lr = lane & 15;
    const int srow = tid >> 6, scol = (tid & 63) * 8;

    const int qrow = q0 + wave * 16 + lr;              // this lane's q row
    float la2[8];
    #pragma unroll
    for (int h = 0; h < 8; ++h)
        la2[h] = -log2f(lbuf[(b * 8 + h) * S_LEN + qrow]) - 3.0f;

    const unsigned short* qbase = Qb + (size_t)(b * S_LEN + qrow) * DM;
    const unsigned short* Kbase = Kb + (size_t)(b * S_LEN) * DM;
    float* obase = outmean + (size_t)(b * S_LEN + qrow) * S_LEN;

    short8 stg[8];
    #pragma unroll
    for (int i = 0; i < 8; ++i) {
        int row = srow + i * 4;
        stg[i] = *reinterpret_cast<const short8*>(Kbase + (size_t)(kc0 + row) * DM + scol);
    }

    for (int t = 0; t < 16; ++t) {
        int kv0 = kc0 + t * 32;
        #pragma unroll
        for (int i = 0; i < 8; ++i) {
            int row = srow + i * 4;
            *reinterpret_cast<short8*>(&k_sh[row][scol]) = stg[i];
        }
        __syncthreads();
        if (t + 1 < 16) {
            #pragma unroll
            for (int i = 0; i < 8; ++i) {
                int row = srow + i * 4;
                stg[i] = *reinterpret_cast<const short8*>(Kbase + (size_t)(kv0 + 32 + row) * DM + scol);
            }
        }
        float macc[2][4];
        #pragma unroll
        for (int f = 0; f < 2; ++f)
            #pragma unroll
            for (int r = 0; r < 4; ++r) macc[f][r] = 0.f;
        #pragma unroll
        for (int h = 0; h < 8; ++h) {
            const unsigned short* qp = qbase + h * 64;
            short8 qf0 = *reinterpret_cast<const short8*>(qp + g * 8);
            short8 qf1 = *reinterpret_cast<const short8*>(qp + 32 + g * 8);
            f32x4 s[2];
            s[0] = (f32x4){0.f, 0.f, 0.f, 0.f};
            s[1] = (f32x4){0.f, 0.f, 0.f, 0.f};
            __builtin_amdgcn_s_setprio(1);
            #pragma unroll
            for (int f = 0; f < 2; ++f) {
                short8 kf0 = *reinterpret_cast<const short8*>(&k_sh[f * 16 + lr][h * 64 + g * 8]);
                s[f] = __builtin_amdgcn_mfma_f32_16x16x32_bf16(kf0, qf0, s[f], 0, 0, 0);
                short8 kf1 = *reinterpret_cast<const short8*>(&k_sh[f * 16 + lr][h * 64 + 32 + g * 8]);
                s[f] = __builtin_amdgcn_mfma_f32_16x16x32_bf16(kf1, qf1, s[f], 0, 0, 0);
            }
            __builtin_amdgcn_s_setprio(0);
            #pragma unroll
            for (int f = 0; f < 2; ++f)
                #pragma unroll
                for (int r = 0; r < 4; ++r)
                    macc[f][r] += __builtin_amdgcn_exp2f(s[f][r] + la2[h]);
        }
        #pragma unroll
        for (int f = 0; f < 2; ++f) {
            float4 ov;
            ov.x = macc[f][0]; ov.y = macc[f][1]; ov.z = macc[f][2]; ov.w = macc[f][3];
            *reinterpret_cast<float4*>(obase + kv0 + f * 16 + g * 4) = ov;
        }
        __syncthreads();
    }
}

// ---------------- LayerNorm (one wave per row of 512) ----------------
__global__ __launch_bounds__(64) void ln_kernel(
    const float* __restrict__ hbuf, const float* __restrict__ gamma,
    const float* __restrict__ beta, float* __restrict__ dout)
{
    int row = blockIdx.x, lane = threadIdx.x;
    const float* hp = hbuf + (size_t)row * DM + lane * 8;
    float4 v0 = *reinterpret_cast<const float4*>(hp);
    float4 v1 = *reinterpret_cast<const float4*>(hp + 4);
    float s = v0.x + v0.y + v0.z + v0.w + v1.x + v1.y + v1.z + v1.w;
    float ss = v0.x * v0.x + v0.y * v0.y + v0.z * v0.z + v0.w * v0.w
             + v1.x * v1.x + v1.y * v1.y + v1.z * v1.z + v1.w * v1.w;
    #pragma unroll
    for (int d = 32; d; d >>= 1) { s += __shfl_xor(s, d); ss += __shfl_xor(ss, d); }
    float mu = s * (1.f / 512.f);
    float var = ss * (1.f / 512.f) - mu * mu;
    float rstd = rsqrtf(var + 1e-5f);
    float4 g0 = *reinterpret_cast<const float4*>(gamma + lane * 8);
    float4 g1 = *reinterpret_cast<const float4*>(gamma + lane * 8 + 4);
    float4 b0 = *reinterpret_cast<const float4*>(beta + lane * 8);
    float4 b1 = *reinterpret_cast<const float4*>(beta + lane * 8 + 4);
    float4 o0, o1;
    o0.x = (v0.x - mu) * rstd * g0.x + b0.x;
    o0.y = (v0.y - mu) * rstd * g0.y + b0.y;
    o0.z = (v0.z - mu) * rstd * g0.z + b0.z;
    o0.w = (v0.w - mu) * rstd * g0.w + b0.w;
    o1.x = (v1.x - mu) * rstd * g1.x + b1.x;
    o1.y = (v1.y - mu) * rstd * g1.y + b1.y;
    o1.z = (v1.z - mu) * rstd * g1.z + b1.z;
    o1.w = (v1.w - mu) * rstd * g1.w + b1.w;
    float* op = dout + (size_t)row * DM + lane * 8;
    *reinterpret_cast<float4*>(op) = o0;
    *reinterpret_cast<float4*>(op + 4) = o1;
}

extern "C" void kernel_launch(void* const* d_in, const int* in_sizes, int n_in,
                              void* d_out, int out_size, void* d_ws, size_t ws_size,
                              hipStream_t stream)
{
    const float* x   = (const float*)d_in[0];
    const float* cs  = (const float*)d_in[1];
    const float* wq  = (const float*)d_in[2];
    const float* wk  = (const float*)d_in[3];
    const float* wv  = (const float*)d_in[4];
    const float* wo  = (const float*)d_in[5];
    const float* bo  = (const float*)d_in[6];
    const float* wg  = (const float*)d_in[7];
    const float* bg  = (const float*)d_in[8];
    const float* wi  = (const float*)d_in[9];
    const float* bi  = (const float*)d_in[10];
    const float* gam = (const float*)d_in[11];
    const float* bet = (const float*)d_in[12];

    float* out = (float*)d_out;
    float* outmean = out + (size_t)2 * S_LEN * DM;

    char* ws = (char*)d_ws;
    size_t off = 0;
    auto alloc = [&](size_t bytes) { void* p = ws + off; off += (bytes + 255) & ~(size_t)255; return p; };

    unsigned short* wtq = (unsigned short*)alloc((size_t)DM * DM * 2);   // contiguous:
    unsigned short* wtk = (unsigned short*)alloc((size_t)DM * DM * 2);   // wtq|wtk|wtv form
    unsigned short* wtv = (unsigned short*)alloc((size_t)DM * DM * 2);   // a [1536][512] block
    unsigned short* wto = (unsigned short*)alloc((size_t)DM * DM * 2);
    unsigned short* xb  = (unsigned short*)alloc((size_t)2 * S_LEN * DM * 2);
    unsigned short* Qb  = (unsigned short*)alloc((size_t)2 * S_LEN * DM * 2);
    unsigned short* Kb  = (unsigned short*)alloc((size_t)2 * S_LEN * DM * 2);
    unsigned short* Vt  = (unsigned short*)alloc((size_t)2 * S_LEN * DM * 2);
    unsigned short* ctx = (unsigned short*)alloc((size_t)2 * S_LEN * DM * 2);
    float* lbuf = (float*)alloc((size_t)16 * S_LEN * 4);
    float* cwb  = (float*)alloc(64);
    float* iwb  = (float*)alloc((size_t)2 * DM * 4);
    // hbuf aliases Qb+Kb (16 MB f32; both dead after attn_mean; stream-ordered)
    float* hbuf = (float*)Qb;

    convert_w<<<dim3(8, 8, 4), 256, 0, stream>>>(wq, wk, wv, wo, wtq, wtk, wtv, wto);
    convert_x<<<dim3(2048), 256, 0, stream>>>(x, xb);
    gates_kernel<<<dim3(520, 2), 64, 0, stream>>>(cs, wg, bg, wi, bi, cwb, iwb);

    gemm_qkv<<<dim3(64, 24), 256, 0, stream>>>(xb, wtq, cwb, Qb, Kb, Vt);

    attn_ctx<<<dim3(512), 256, 0, stream>>>(Qb, Kb, Vt, lbuf, ctx);
    attn_mean<<<dim3(1024), 256, 0, stream>>>(Qb, Kb, lbuf, outmean);

    gemm_proj<<<dim3(64, 8), 256, 0, stream>>>(ctx, wto, hbuf, bo, iwb, x);
    ln_kernel<<<dim3(2 * S_LEN), 64, 0, stream>>>(hbuf, gam, bet, out);
}